// Round 3
// baseline (441.390 us; speedup 1.0000x reference)
//
#include <hip/hip_runtime.h>
#include <hip/hip_fp16.h>
#include <math.h>

// GATv2 x2 + MLP decoder. Round 17: XCD-partitioned scatter.
//
// R16 post-mortem: counts padding did nothing (122us, hbm 880). Real scatter
// cost: (a) counter+payload split = 2 random lines/edge (R14 embedded = 1);
// (b) WRITE_SIZE 96MB = ~1 writeback per EDGE -> each payload line migrates
// between incoherent per-XCD L2s ~5x as its edges execute on random XCDs.
// Gat/proj micro-opts across R15/R16 all null ("rest" flat 295/296/285) --
// latency-bound, leave untouched this round for clean attribution.
//
// Changes (scatter only):
//  - counter re-embedded in 256B payload row (R14 layout, 1 line/edge).
//  - partition by dst&7 == blockIdx&7: with round-robin block->XCD dispatch
//    (HK chiplet-swizzle assumption, T1/m192) all writes+atomics for a row
//    issue from ONE XCD -> line stays in its L2, single writeback.
//    Reads amplify 8x on dst (51MB, L3-served); src/eattr exec-masked.
//  - falsifiable: success = WRITE_SIZE 96->~20MB, dur 122->~50us.
//    failure = both unchanged -> revert to plain R14 scatter next round.

#define NN 100000
#define NE 1600000
#define SLOT 48
#define ROWU 64        // uints per row (256 B): [0]=count, [4..51]=payload
#define NPART 8
#define NEG_SLOPE 0.2f

// ---- scatter edges into row-CSR (by dst), XCD-partitioned ----
__global__ void scatter_kernel(const int* __restrict__ src, const int* __restrict__ dst,
                               const float* __restrict__ eattr,
                               unsigned* __restrict__ csr) {
    int part = blockIdx.x & (NPART - 1);
    int chunk = blockIdx.x >> 3;
    int e = chunk * blockDim.x + threadIdx.x;   // grid exact: 8 x 6250 x 256
    int d = dst[e];
    if ((d & (NPART - 1)) != part) return;
    unsigned* row = csr + (size_t)d * ROWU;
    int pos = atomicAdd((int*)row, 1);
    if (pos < SLOT) {
        unsigned hb = __half_as_ushort(__float2half_rn(eattr[e]));
        row[4 + pos] = ((unsigned)src[e] << 15) | (hb >> 1);
    }
}

__device__ __forceinline__ float pk_ea(unsigned p) {
    return __half2float(__ushort_as_half((unsigned short)((p & 0x7FFFu) << 1)));
}
__device__ __forceinline__ float lrelu(float v) {
    return (v >= 0.f) ? v : NEG_SLOPE * v;
}

// ---- dense proj (layer 1): xl(fp16)=x@Wl+bl, xr=x@Wr+br, 4 rows/thread ----
template <int K>
__global__ void proj_kernel(const float* __restrict__ x,
                            const float* __restrict__ Wl, const float* __restrict__ bl,
                            const float* __restrict__ Wr, const float* __restrict__ br,
                            __half* __restrict__ xl, float* __restrict__ xr) {
    __shared__ __align__(16) float sWl[K * 32];
    __shared__ __align__(16) float sWr[K * 32];
    __shared__ float sb[64];
    for (int i = threadIdx.x; i < K * 32; i += blockDim.x) {
        int k = i >> 5, col = i & 31;
        int p = (((k >> 2) ^ (col & 7)) << 2) | (k & 3);   // swizzled k index
        sWl[col * K + p] = Wl[i];
        sWr[col * K + p] = Wr[i];
    }
    if (threadIdx.x < 32) sb[threadIdx.x] = bl[threadIdx.x];
    else if (threadIdx.x < 64) sb[threadIdx.x] = br[threadIdx.x - 32];
    __syncthreads();
    int t = blockIdx.x * blockDim.x + threadIdx.x;
    int g = t >> 5, col = t & 31;
    int row0 = g * 4;
    if (row0 >= NN) return;                 // grid exact: never taken
    const float4* x0 = (const float4*)(x + (size_t)(row0 + 0) * K);
    const float4* x1 = (const float4*)(x + (size_t)(row0 + 1) * K);
    const float4* x2 = (const float4*)(x + (size_t)(row0 + 2) * K);
    const float4* x3 = (const float4*)(x + (size_t)(row0 + 3) * K);
    const float4* wl4 = (const float4*)(sWl + col * K);
    const float4* wr4 = (const float4*)(sWr + col * K);
    int swz = col & 7;
    float al0 = 0.f, al1 = 0.f, al2 = 0.f, al3 = 0.f;
    float ar0 = 0.f, ar1 = 0.f, ar2 = 0.f, ar3 = 0.f;
#pragma unroll 4
    for (int k4 = 0; k4 < K / 4; k4++) {
        float4 wl = wl4[k4 ^ swz];
        float4 wr = wr4[k4 ^ swz];
        float4 a = x0[k4];
        float4 b = x1[k4];
        float4 c = x2[k4];
        float4 d = x3[k4];
        al0 = fmaf(a.x, wl.x, al0); al0 = fmaf(a.y, wl.y, al0);
        al0 = fmaf(a.z, wl.z, al0); al0 = fmaf(a.w, wl.w, al0);
        ar0 = fmaf(a.x, wr.x, ar0); ar0 = fmaf(a.y, wr.y, ar0);
        ar0 = fmaf(a.z, wr.z, ar0); ar0 = fmaf(a.w, wr.w, ar0);
        al1 = fmaf(b.x, wl.x, al1); al1 = fmaf(b.y, wl.y, al1);
        al1 = fmaf(b.z, wl.z, al1); al1 = fmaf(b.w, wl.w, al1);
        ar1 = fmaf(b.x, wr.x, ar1); ar1 = fmaf(b.y, wr.y, ar1);
        ar1 = fmaf(b.z, wr.z, ar1); ar1 = fmaf(b.w, wr.w, ar1);
        al2 = fmaf(c.x, wl.x, al2); al2 = fmaf(c.y, wl.y, al2);
        al2 = fmaf(c.z, wl.z, al2); al2 = fmaf(c.w, wl.w, al2);
        ar2 = fmaf(c.x, wr.x, ar2); ar2 = fmaf(c.y, wr.y, ar2);
        ar2 = fmaf(c.z, wr.z, ar2); ar2 = fmaf(c.w, wr.w, ar2);
        al3 = fmaf(d.x, wl.x, al3); al3 = fmaf(d.y, wl.y, al3);
        al3 = fmaf(d.z, wl.z, al3); al3 = fmaf(d.w, wl.w, al3);
        ar3 = fmaf(d.x, wr.x, ar3); ar3 = fmaf(d.y, wr.y, ar3);
        ar3 = fmaf(d.w, wr.w, ar3); ar3 = fmaf(d.z, wr.z, ar3);
    }
    float bls = sb[col], brs = sb[32 + col];
    xl[(size_t)(row0 + 0) * 32 + col] = __float2half_rn(al0 + bls);
    xr[(size_t)(row0 + 0) * 32 + col] = ar0 + brs;
    xl[(size_t)(row0 + 1) * 32 + col] = __float2half_rn(al1 + bls);
    xr[(size_t)(row0 + 1) * 32 + col] = ar1 + brs;
    xl[(size_t)(row0 + 2) * 32 + col] = __float2half_rn(al2 + bls);
    xr[(size_t)(row0 + 2) * 32 + col] = ar2 + brs;
    xl[(size_t)(row0 + 3) * 32 + col] = __float2half_rn(al3 + bls);
    xr[(size_t)(row0 + 3) * 32 + col] = ar3 + brs;
}

// ---- GAT core, 8 lanes/edge x 4 edges: returns h[4k..4k+3] per lane ----
// lane L in [0,32): k = L&7 (channel quad), j = L>>3 (edge slot).
// 2-deep pipeline: gather for iter i+1 issued before compute of iter i;
// payload word for iter i+2 prefetched. Invalid slots gather xl[0] (finite)
// and are masked to weight 0, so uninitialized payload never reaches math.
__device__ __forceinline__ void gat_core4(const unsigned* __restrict__ csr,
                                          const __half* xl, const float* xr,
                                          const float* We, const float* att,
                                          const float* bias, int node, int L,
                                          float h[4]) {
    int k = L & 7, j = L >> 3;
    const unsigned* row = csr + (size_t)node * ROWU;
    int cnt = (int)row[0];
    int deg = (cnt < SLOT) ? cnt : SLOT;
    float4 we = ((const float4*)We)[k];
    float4 at = ((const float4*)att)[k];
    float4 xrc = ((const float4*)(xr + (size_t)node * 32))[k];
    ushort4 sq = ((const ushort4*)(xl + (size_t)node * 32))[k];
    float sx0 = __half2float(__ushort_as_half(sq.x));
    float sx1 = __half2float(__ushort_as_half(sq.y));
    float sx2 = __half2float(__ushort_as_half(sq.z));
    float sx3 = __half2float(__ushort_as_half(sq.w));
    float ssum = 0.f, a0 = 0.f, a1 = 0.f, a2 = 0.f, a3 = 0.f, easum = 0.f;
    // pipeline prologue
    unsigned pv_c = row[4 + j];
    int n1 = j + 4; if (n1 > SLOT - 1) n1 = SLOT - 1;
    unsigned pv_n = row[4 + n1];
    bool val_c = j < deg;
    int s_c = val_c ? (int)(pv_c >> 15) : 0;
    ushort4 q_c = ((const ushort4*)(xl + (size_t)s_c * 32))[k];
    for (int base = 0; base < deg; base += 4) {
        int idx = base + j;
        // issue next gather + prefetch payload two ahead
        bool val_n = (idx + 4) < deg;
        int s_n = val_n ? (int)(pv_n >> 15) : 0;
        ushort4 q_n = ((const ushort4*)(xl + (size_t)s_n * 32))[k];
        int n2 = idx + 8; if (n2 > SLOT - 1) n2 = SLOT - 1;
        unsigned pv_n2 = row[4 + n2];
        // compute with current
        float ea = pk_ea(pv_c);
        float x0 = __half2float(__ushort_as_half(q_c.x));
        float x1 = __half2float(__ushort_as_half(q_c.y));
        float x2 = __half2float(__ushort_as_half(q_c.z));
        float x3 = __half2float(__ushort_as_half(q_c.w));
        float p;
        p  = at.x * lrelu(fmaf(ea, we.x, x0 + xrc.x));
        p  = fmaf(at.y, lrelu(fmaf(ea, we.y, x1 + xrc.y)), p);
        p  = fmaf(at.z, lrelu(fmaf(ea, we.z, x2 + xrc.z)), p);
        p  = fmaf(at.w, lrelu(fmaf(ea, we.w, x3 + xrc.w)), p);
        p += __shfl_xor(p, 1);
        p += __shfl_xor(p, 2);
        float w = val_c ? __expf(p) : 0.f;
        ssum += w;
        easum += val_c ? ea : 0.f;
        a0 = fmaf(w, x0, a0);
        a1 = fmaf(w, x1, a1);
        a2 = fmaf(w, x2, a2);
        a3 = fmaf(w, x3, a3);
        // rotate pipeline
        pv_c = pv_n; pv_n = pv_n2; q_c = q_n; val_c = val_n;
    }
    // reduce across the 4 edge slots (lanes xor 8, 16)
    ssum  += __shfl_xor(ssum, 8);   ssum  += __shfl_xor(ssum, 16);
    easum += __shfl_xor(easum, 8);  easum += __shfl_xor(easum, 16);
    a0 += __shfl_xor(a0, 8);  a0 += __shfl_xor(a0, 16);
    a1 += __shfl_xor(a1, 8);  a1 += __shfl_xor(a1, 16);
    a2 += __shfl_xor(a2, 8);  a2 += __shfl_xor(a2, 16);
    a3 += __shfl_xor(a3, 8);  a3 += __shfl_xor(a3, 16);
    // self-loop: ea = mean of incoming eattr (deg==0 safe: ssum was 0)
    {
        float ea0 = easum / fmaxf((float)cnt, 1.f);
        float p;
        p  = at.x * lrelu(fmaf(ea0, we.x, sx0 + xrc.x));
        p  = fmaf(at.y, lrelu(fmaf(ea0, we.y, sx1 + xrc.y)), p);
        p  = fmaf(at.z, lrelu(fmaf(ea0, we.z, sx2 + xrc.z)), p);
        p  = fmaf(at.w, lrelu(fmaf(ea0, we.w, sx3 + xrc.w)), p);
        p += __shfl_xor(p, 1);
        p += __shfl_xor(p, 2);
        float w = __expf(p);
        ssum += w;
        a0 = fmaf(w, sx0, a0);
        a1 = fmaf(w, sx1, a1);
        a2 = fmaf(w, sx2, a2);
        a3 = fmaf(w, sx3, a3);
    }
    float4 bq = ((const float4*)bias)[k];
    float inv = 1.f / ssum;
    h[0] = a0 * inv + bq.x;
    h[1] = a1 * inv + bq.y;
    h[2] = a2 * inv + bq.z;
    h[3] = a3 * inv + bq.w;
}

// wave-local publish of h to LDS: lanes 0-7 of each 32-lane group write,
// all 32 read. Same wave -> DS in-order; waitcnt + clobber stop reordering.
#define HBUF_FENCE() do { \
    asm volatile("s_waitcnt lgkmcnt(0)" ::: "memory"); \
    __builtin_amdgcn_sched_barrier(0); \
} while (0)

// ---- gat1 + proj2: h via 1KB LDS exchange; W^T swizzled float4 reads ----
__global__ void gat1_proj2_kernel(const unsigned* __restrict__ csr,
                                  const __half* __restrict__ xl, const float* __restrict__ xr,
                                  const float* __restrict__ We, const float* __restrict__ att,
                                  const float* __restrict__ bias,
                                  const float* __restrict__ Wl2, const float* __restrict__ bl2,
                                  const float* __restrict__ Wr2, const float* __restrict__ br2,
                                  __half* __restrict__ xl2, float* __restrict__ xr2) {
    __shared__ __align__(16) float sWl[1024];   // Wl2^T [L][cc], cc-quads swizzled
    __shared__ __align__(16) float sWr[1024];
    __shared__ float4 hbuf[8][8];               // 8 node-groups x 32 ch
    for (int i = threadIdx.x; i < 1024; i += blockDim.x) {
        int cc = i >> 5, Lc = i & 31;
        int p = (((cc >> 2) ^ (Lc & 7)) << 2) | (cc & 3);
        sWl[Lc * 32 + p] = Wl2[i];
        sWr[Lc * 32 + p] = Wr2[i];
    }
    __syncthreads();
    int t = blockIdx.x * blockDim.x + threadIdx.x;
    int node = t >> 5, L = t & 31;
    if (node >= NN) return;                     // grid exact: never taken
    float h[4];
    gat_core4(csr, xl, xr, We, att, bias, node, L, h);
    int nl = threadIdx.x >> 5;
    if (L < 8) hbuf[nl][L] = make_float4(h[0], h[1], h[2], h[3]);
    HBUF_FENCE();
    const float4* hv4 = hbuf[nl];
    const float4* wl4 = (const float4*)(sWl + L * 32);
    const float4* wr4 = (const float4*)(sWr + L * 32);
    int swz = L & 7;
    float al = bl2[L], ar = br2[L];
#pragma unroll
    for (int c4 = 0; c4 < 8; c4++) {
        float4 hv = hv4[c4];                    // broadcast read (same addr)
        float4 wl = wl4[c4 ^ swz];
        float4 wr = wr4[c4 ^ swz];
        al = fmaf(hv.x, wl.x, al); al = fmaf(hv.y, wl.y, al);
        al = fmaf(hv.z, wl.z, al); al = fmaf(hv.w, wl.w, al);
        ar = fmaf(hv.x, wr.x, ar); ar = fmaf(hv.y, wr.y, ar);
        ar = fmaf(hv.z, wr.z, ar); ar = fmaf(hv.w, wr.w, ar);
    }
    xl2[(size_t)node * 32 + L] = __float2half_rn(al);
    xr2[(size_t)node * 32 + L] = ar;
}

// ---- gat2 + decoder: h via LDS exchange; Wd1^T swizzled; in-wave MLP ----
__global__ void gat2_dec_kernel(const unsigned* __restrict__ csr,
                                const __half* __restrict__ xl, const float* __restrict__ xr,
                                const float* __restrict__ We, const float* __restrict__ att,
                                const float* __restrict__ bias,
                                const float* __restrict__ Wd1, const float* __restrict__ bd1,
                                const float* __restrict__ Wd2, const float* __restrict__ bd2,
                                float* __restrict__ out) {
    __shared__ __align__(16) float sWd1[1024];  // Wd1^T [L][cc], swizzled
    __shared__ float sWd2[64];
    __shared__ float4 hbuf[8][8];
    for (int i = threadIdx.x; i < 1024; i += blockDim.x) {
        int cc = i >> 5, Lc = i & 31;
        int p = (((cc >> 2) ^ (Lc & 7)) << 2) | (cc & 3);
        sWd1[Lc * 32 + p] = Wd1[i];
    }
    if (threadIdx.x < 64) sWd2[threadIdx.x] = Wd2[threadIdx.x];
    __syncthreads();
    int t = blockIdx.x * blockDim.x + threadIdx.x;
    int node = t >> 5, L = t & 31;
    if (node >= NN) return;                     // grid exact: never taken
    float h[4];
    gat_core4(csr, xl, xr, We, att, bias, node, L, h);
    int nl = threadIdx.x >> 5;
    if (L < 8) hbuf[nl][L] = make_float4(h[0], h[1], h[2], h[3]);
    HBUF_FENCE();
    const float4* hv4 = hbuf[nl];
    const float4* wd4 = (const float4*)(sWd1 + L * 32);
    int swz = L & 7;
    float d1 = bd1[L];
#pragma unroll
    for (int c4 = 0; c4 < 8; c4++) {
        float4 hv = hv4[c4];
        float4 wd = wd4[c4 ^ swz];
        d1 = fmaf(hv.x, wd.x, d1); d1 = fmaf(hv.y, wd.y, d1);
        d1 = fmaf(hv.z, wd.z, d1); d1 = fmaf(hv.w, wd.w, d1);
    }
    float hid = fmaxf(d1, 0.f);
    float o0 = hid * sWd2[L * 2 + 0];
    float o1 = hid * sWd2[L * 2 + 1];
    o0 += __shfl_xor(o0, 1);   o1 += __shfl_xor(o1, 1);
    o0 += __shfl_xor(o0, 2);   o1 += __shfl_xor(o1, 2);
    o0 += __shfl_xor(o0, 4);   o1 += __shfl_xor(o1, 4);
    o0 += __shfl_xor(o0, 8);   o1 += __shfl_xor(o1, 8);
    o0 += __shfl_xor(o0, 16);  o1 += __shfl_xor(o1, 16);
    if (L == 0) {
        out[(size_t)node * 2 + 0] = o0 + bd2[0];
        out[(size_t)node * 2 + 1] = o1 + bd2[1];
    }
}

extern "C" void kernel_launch(void* const* d_in, const int* in_sizes, int n_in,
                              void* d_out, int out_size, void* d_ws, size_t ws_size,
                              hipStream_t stream) {
    const float* x     = (const float*)d_in[0];
    const int*   src   = (const int*)d_in[1];
    const int*   dst   = src + NE;
    const float* eattr = (const float*)d_in[2];
    const float* Wl1 = (const float*)d_in[3],  *bl1 = (const float*)d_in[4];
    const float* Wr1 = (const float*)d_in[5],  *br1 = (const float*)d_in[6];
    const float* We1 = (const float*)d_in[7],  *att1 = (const float*)d_in[8];
    const float* b1  = (const float*)d_in[9];
    const float* Wl2 = (const float*)d_in[10], *bl2 = (const float*)d_in[11];
    const float* Wr2 = (const float*)d_in[12], *br2 = (const float*)d_in[13];
    const float* We2 = (const float*)d_in[14], *att2 = (const float*)d_in[15];
    const float* b2  = (const float*)d_in[16];
    const float* Wd1 = (const float*)d_in[17], *bd1 = (const float*)d_in[18];
    const float* Wd2 = (const float*)d_in[19], *bd2 = (const float*)d_in[20];
    float* out = (float*)d_out;

    // workspace layout (~45 MB)
    char* w = (char*)d_ws;
    unsigned* csr = (unsigned*)w;  w += (size_t)NN * ROWU * 4;   // 25.6 MB
    __half*   xl  = (__half*)w;    w += (size_t)NN * 32 * 2;
    float*    xr  = (float*)w;     w += (size_t)NN * 32 * 4;
    __half*   xl2 = (__half*)w;    w += (size_t)NN * 32 * 2;
    float*    xr2 = (float*)w;     w += (size_t)NN * 32 * 4;

    const int B = 256;
    const int gE   = (NE / B) * NPART;    // 50000: 8 partitions x 6250 chunks
    const int gN32 = (NN * 32) / B;       // 12500
    const int gP   = (NN / 4 * 32) / B;   // 3125 (proj: 4 rows/thread)

    // ---- CSR build (counts live in row word 0 -> zero whole region) ----
    hipMemsetAsync(csr, 0, (size_t)NN * ROWU * 4, stream);
    scatter_kernel<<<gE, B, 0, stream>>>(src, dst, eattr, csr);

    // ---- layer 1 projections ----
    proj_kernel<128><<<gP, B, 0, stream>>>(x, Wl1, bl1, Wr1, br1, xl, xr);

    // ---- layer 1 aggregate + layer 2 projections ----
    gat1_proj2_kernel<<<gN32, B, 0, stream>>>(csr, xl, xr, We1, att1, b1,
                                              Wl2, bl2, Wr2, br2, xl2, xr2);

    // ---- layer 2 aggregate + decoder ----
    gat2_dec_kernel<<<gN32, B, 0, stream>>>(csr, xl2, xr2, We2, att2, b2,
                                            Wd1, bd1, Wd2, bd2, out);
}

// Round 4
// 363.881 us; speedup vs baseline: 1.2130x; 1.2130x over previous
//
#include <hip/hip_runtime.h>
#include <hip/hip_fp16.h>
#include <math.h>

// GATv2 x2 + MLP decoder. Round 18: revert scatter, overlap it with proj.
//
// R17 post-mortem: XCD partitioning refuted -- FETCH 9.8->74MB (8x read amp
// as predicted) but WRITE_SIZE stayed ~90MB, dur 122->153. Across R14-R17
// WRITE_SIZE ~= NE x 60B regardless of layout => L2 is no-write-allocate on
// store miss: every scattered 4B store/atomic costs its own sector write.
// (R14 FETCH 9.8MB also too small for store line-fills -- confirms.)
// Scatter ~88us (R14 form) is a transaction-rate floor for this algorithm.
//
// Changes:
//  - scatter reverted to R14 embedded-counter row-CSR (1 random line/edge).
//  - scatter fused as per-block tail of proj: single stream serializes
//    separate kernels (events forbidden in graph capture), but within one
//    kernel, blocks at staggered phases co-schedule latency-bound scatter
//    (VALU 0.6%) with VALU-bound proj on the same SIMDs (m114 mechanism).
//    Scatter's dst/src/eattr loads are proj-independent -> hoisted early.
//  - gat kernels byte-for-byte unchanged (attribution: top-5 should now
//    surface them).
// Predict: fused dispatch 100-135us (vs 88+proj serial), total ~340-365.
// Failure: fused >=150us -> split back next round.

#define NN 100000
#define NE 1600000
#define SLOT 48
#define ROWU 64        // uints per row (256 B): [0]=count, [4..51]=payload
#define NEG_SLOPE 0.2f

__device__ __forceinline__ float pk_ea(unsigned p) {
    return __half2float(__ushort_as_half((unsigned short)((p & 0x7FFFu) << 1)));
}
__device__ __forceinline__ float lrelu(float v) {
    return (v >= 0.f) ? v : NEG_SLOPE * v;
}

// ---- fused: dense proj (4 rows/thread) + scatter tail (512 edges/block) ----
// proj: xl(fp16)=x@Wl+bl, xr=x@Wr+br. LDS holds W transposed, k-quads
// XOR-swizzled so the wave's 32 cols hit 8 distinct bank-quads on b128 reads.
// scatter: R14 embedded-counter row-CSR, per-edge atomic slot claim.
template <int K>
__global__ void proj_scatter_kernel(const float* __restrict__ x,
                                    const float* __restrict__ Wl, const float* __restrict__ bl,
                                    const float* __restrict__ Wr, const float* __restrict__ br,
                                    __half* __restrict__ xl, float* __restrict__ xr,
                                    const int* __restrict__ src, const int* __restrict__ dst,
                                    const float* __restrict__ eattr,
                                    unsigned* __restrict__ csr) {
    __shared__ __align__(16) float sWl[K * 32];
    __shared__ __align__(16) float sWr[K * 32];
    __shared__ float sb[64];
    for (int i = threadIdx.x; i < K * 32; i += blockDim.x) {
        int k = i >> 5, col = i & 31;
        int p = (((k >> 2) ^ (col & 7)) << 2) | (k & 3);   // swizzled k index
        sWl[col * K + p] = Wl[i];
        sWr[col * K + p] = Wr[i];
    }
    if (threadIdx.x < 32) sb[threadIdx.x] = bl[threadIdx.x];
    else if (threadIdx.x < 64) sb[threadIdx.x] = br[threadIdx.x - 32];
    __syncthreads();
    int t = blockIdx.x * blockDim.x + threadIdx.x;
    int g = t >> 5, col = t & 31;
    int row0 = g * 4;                       // grid exact: row0 always < NN
    {
        const float4* x0 = (const float4*)(x + (size_t)(row0 + 0) * K);
        const float4* x1 = (const float4*)(x + (size_t)(row0 + 1) * K);
        const float4* x2 = (const float4*)(x + (size_t)(row0 + 2) * K);
        const float4* x3 = (const float4*)(x + (size_t)(row0 + 3) * K);
        const float4* wl4 = (const float4*)(sWl + col * K);
        const float4* wr4 = (const float4*)(sWr + col * K);
        int swz = col & 7;
        float al0 = 0.f, al1 = 0.f, al2 = 0.f, al3 = 0.f;
        float ar0 = 0.f, ar1 = 0.f, ar2 = 0.f, ar3 = 0.f;
#pragma unroll 4
        for (int k4 = 0; k4 < K / 4; k4++) {
            float4 wl = wl4[k4 ^ swz];
            float4 wr = wr4[k4 ^ swz];
            float4 a = x0[k4];
            float4 b = x1[k4];
            float4 c = x2[k4];
            float4 d = x3[k4];
            al0 = fmaf(a.x, wl.x, al0); al0 = fmaf(a.y, wl.y, al0);
            al0 = fmaf(a.z, wl.z, al0); al0 = fmaf(a.w, wl.w, al0);
            ar0 = fmaf(a.x, wr.x, ar0); ar0 = fmaf(a.y, wr.y, ar0);
            ar0 = fmaf(a.z, wr.z, ar0); ar0 = fmaf(a.w, wr.w, ar0);
            al1 = fmaf(b.x, wl.x, al1); al1 = fmaf(b.y, wl.y, al1);
            al1 = fmaf(b.z, wl.z, al1); al1 = fmaf(b.w, wl.w, al1);
            ar1 = fmaf(b.x, wr.x, ar1); ar1 = fmaf(b.y, wr.y, ar1);
            ar1 = fmaf(b.z, wr.z, ar1); ar1 = fmaf(b.w, wr.w, ar1);
            al2 = fmaf(c.x, wl.x, al2); al2 = fmaf(c.y, wl.y, al2);
            al2 = fmaf(c.z, wl.z, al2); al2 = fmaf(c.w, wl.w, al2);
            ar2 = fmaf(c.x, wr.x, ar2); ar2 = fmaf(c.y, wr.y, ar2);
            ar2 = fmaf(c.z, wr.z, ar2); ar2 = fmaf(c.w, wr.w, ar2);
            al3 = fmaf(d.x, wl.x, al3); al3 = fmaf(d.y, wl.y, al3);
            al3 = fmaf(d.z, wl.z, al3); al3 = fmaf(d.w, wl.w, al3);
            ar3 = fmaf(d.x, wr.x, ar3); ar3 = fmaf(d.y, wr.y, ar3);
            ar3 = fmaf(d.z, wr.z, ar3); ar3 = fmaf(d.w, wr.w, ar3);
        }
        float bls = sb[col], brs = sb[32 + col];
        xl[(size_t)(row0 + 0) * 32 + col] = __float2half_rn(al0 + bls);
        xr[(size_t)(row0 + 0) * 32 + col] = ar0 + brs;
        xl[(size_t)(row0 + 1) * 32 + col] = __float2half_rn(al1 + bls);
        xr[(size_t)(row0 + 1) * 32 + col] = ar1 + brs;
        xl[(size_t)(row0 + 2) * 32 + col] = __float2half_rn(al2 + bls);
        xr[(size_t)(row0 + 2) * 32 + col] = ar2 + brs;
        xl[(size_t)(row0 + 3) * 32 + col] = __float2half_rn(al3 + bls);
        xr[(size_t)(row0 + 3) * 32 + col] = ar3 + brs;
    }
    // ---- scatter tail: this block's 512-edge chunk (grid exact: 3125*512=NE)
#pragma unroll
    for (int i = 0; i < 2; i++) {
        int e = blockIdx.x * 512 + i * 256 + threadIdx.x;
        int d = dst[e];
        unsigned* row = csr + (size_t)d * ROWU;
        int pos = atomicAdd((int*)row, 1);
        if (pos < SLOT) {
            unsigned hb = __half_as_ushort(__float2half_rn(eattr[e]));
            row[4 + pos] = ((unsigned)src[e] << 15) | (hb >> 1);
        }
    }
}

// ---- GAT core, 8 lanes/edge x 4 edges: returns h[4k..4k+3] per lane ----
// lane L in [0,32): k = L&7 (channel quad), j = L>>3 (edge slot).
// 2-deep pipeline: gather for iter i+1 issued before compute of iter i;
// payload word for iter i+2 prefetched. Invalid slots gather xl[0] (finite)
// and are masked to weight 0, so uninitialized payload never reaches math.
__device__ __forceinline__ void gat_core4(const unsigned* __restrict__ csr,
                                          const __half* xl, const float* xr,
                                          const float* We, const float* att,
                                          const float* bias, int node, int L,
                                          float h[4]) {
    int k = L & 7, j = L >> 3;
    const unsigned* row = csr + (size_t)node * ROWU;
    int cnt = (int)row[0];
    int deg = (cnt < SLOT) ? cnt : SLOT;
    float4 we = ((const float4*)We)[k];
    float4 at = ((const float4*)att)[k];
    float4 xrc = ((const float4*)(xr + (size_t)node * 32))[k];
    ushort4 sq = ((const ushort4*)(xl + (size_t)node * 32))[k];
    float sx0 = __half2float(__ushort_as_half(sq.x));
    float sx1 = __half2float(__ushort_as_half(sq.y));
    float sx2 = __half2float(__ushort_as_half(sq.z));
    float sx3 = __half2float(__ushort_as_half(sq.w));
    float ssum = 0.f, a0 = 0.f, a1 = 0.f, a2 = 0.f, a3 = 0.f, easum = 0.f;
    // pipeline prologue
    unsigned pv_c = row[4 + j];
    int n1 = j + 4; if (n1 > SLOT - 1) n1 = SLOT - 1;
    unsigned pv_n = row[4 + n1];
    bool val_c = j < deg;
    int s_c = val_c ? (int)(pv_c >> 15) : 0;
    ushort4 q_c = ((const ushort4*)(xl + (size_t)s_c * 32))[k];
    for (int base = 0; base < deg; base += 4) {
        int idx = base + j;
        // issue next gather + prefetch payload two ahead
        bool val_n = (idx + 4) < deg;
        int s_n = val_n ? (int)(pv_n >> 15) : 0;
        ushort4 q_n = ((const ushort4*)(xl + (size_t)s_n * 32))[k];
        int n2 = idx + 8; if (n2 > SLOT - 1) n2 = SLOT - 1;
        unsigned pv_n2 = row[4 + n2];
        // compute with current
        float ea = pk_ea(pv_c);
        float x0 = __half2float(__ushort_as_half(q_c.x));
        float x1 = __half2float(__ushort_as_half(q_c.y));
        float x2 = __half2float(__ushort_as_half(q_c.z));
        float x3 = __half2float(__ushort_as_half(q_c.w));
        float p;
        p  = at.x * lrelu(fmaf(ea, we.x, x0 + xrc.x));
        p  = fmaf(at.y, lrelu(fmaf(ea, we.y, x1 + xrc.y)), p);
        p  = fmaf(at.z, lrelu(fmaf(ea, we.z, x2 + xrc.z)), p);
        p  = fmaf(at.w, lrelu(fmaf(ea, we.w, x3 + xrc.w)), p);
        p += __shfl_xor(p, 1);
        p += __shfl_xor(p, 2);
        float w = val_c ? __expf(p) : 0.f;
        ssum += w;
        easum += val_c ? ea : 0.f;
        a0 = fmaf(w, x0, a0);
        a1 = fmaf(w, x1, a1);
        a2 = fmaf(w, x2, a2);
        a3 = fmaf(w, x3, a3);
        // rotate pipeline
        pv_c = pv_n; pv_n = pv_n2; q_c = q_n; val_c = val_n;
    }
    // reduce across the 4 edge slots (lanes xor 8, 16)
    ssum  += __shfl_xor(ssum, 8);   ssum  += __shfl_xor(ssum, 16);
    easum += __shfl_xor(easum, 8);  easum += __shfl_xor(easum, 16);
    a0 += __shfl_xor(a0, 8);  a0 += __shfl_xor(a0, 16);
    a1 += __shfl_xor(a1, 8);  a1 += __shfl_xor(a1, 16);
    a2 += __shfl_xor(a2, 8);  a2 += __shfl_xor(a2, 16);
    a3 += __shfl_xor(a3, 8);  a3 += __shfl_xor(a3, 16);
    // self-loop: ea = mean of incoming eattr (deg==0 safe: ssum was 0)
    {
        float ea0 = easum / fmaxf((float)cnt, 1.f);
        float p;
        p  = at.x * lrelu(fmaf(ea0, we.x, sx0 + xrc.x));
        p  = fmaf(at.y, lrelu(fmaf(ea0, we.y, sx1 + xrc.y)), p);
        p  = fmaf(at.z, lrelu(fmaf(ea0, we.z, sx2 + xrc.z)), p);
        p  = fmaf(at.w, lrelu(fmaf(ea0, we.w, sx3 + xrc.w)), p);
        p += __shfl_xor(p, 1);
        p += __shfl_xor(p, 2);
        float w = __expf(p);
        ssum += w;
        a0 = fmaf(w, sx0, a0);
        a1 = fmaf(w, sx1, a1);
        a2 = fmaf(w, sx2, a2);
        a3 = fmaf(w, sx3, a3);
    }
    float4 bq = ((const float4*)bias)[k];
    float inv = 1.f / ssum;
    h[0] = a0 * inv + bq.x;
    h[1] = a1 * inv + bq.y;
    h[2] = a2 * inv + bq.z;
    h[3] = a3 * inv + bq.w;
}

// wave-local publish of h to LDS: lanes 0-7 of each 32-lane group write,
// all 32 read. Same wave -> DS in-order; waitcnt + clobber stop reordering.
#define HBUF_FENCE() do { \
    asm volatile("s_waitcnt lgkmcnt(0)" ::: "memory"); \
    __builtin_amdgcn_sched_barrier(0); \
} while (0)

// ---- gat1 + proj2: h via 1KB LDS exchange; W^T swizzled float4 reads ----
__global__ void gat1_proj2_kernel(const unsigned* __restrict__ csr,
                                  const __half* __restrict__ xl, const float* __restrict__ xr,
                                  const float* __restrict__ We, const float* __restrict__ att,
                                  const float* __restrict__ bias,
                                  const float* __restrict__ Wl2, const float* __restrict__ bl2,
                                  const float* __restrict__ Wr2, const float* __restrict__ br2,
                                  __half* __restrict__ xl2, float* __restrict__ xr2) {
    __shared__ __align__(16) float sWl[1024];   // Wl2^T [L][cc], cc-quads swizzled
    __shared__ __align__(16) float sWr[1024];
    __shared__ float4 hbuf[8][8];               // 8 node-groups x 32 ch
    for (int i = threadIdx.x; i < 1024; i += blockDim.x) {
        int cc = i >> 5, Lc = i & 31;
        int p = (((cc >> 2) ^ (Lc & 7)) << 2) | (cc & 3);
        sWl[Lc * 32 + p] = Wl2[i];
        sWr[Lc * 32 + p] = Wr2[i];
    }
    __syncthreads();
    int t = blockIdx.x * blockDim.x + threadIdx.x;
    int node = t >> 5, L = t & 31;
    if (node >= NN) return;                     // grid exact: never taken
    float h[4];
    gat_core4(csr, xl, xr, We, att, bias, node, L, h);
    int nl = threadIdx.x >> 5;
    if (L < 8) hbuf[nl][L] = make_float4(h[0], h[1], h[2], h[3]);
    HBUF_FENCE();
    const float4* hv4 = hbuf[nl];
    const float4* wl4 = (const float4*)(sWl + L * 32);
    const float4* wr4 = (const float4*)(sWr + L * 32);
    int swz = L & 7;
    float al = bl2[L], ar = br2[L];
#pragma unroll
    for (int c4 = 0; c4 < 8; c4++) {
        float4 hv = hv4[c4];                    // broadcast read (same addr)
        float4 wl = wl4[c4 ^ swz];
        float4 wr = wr4[c4 ^ swz];
        al = fmaf(hv.x, wl.x, al); al = fmaf(hv.y, wl.y, al);
        al = fmaf(hv.z, wl.z, al); al = fmaf(hv.w, wl.w, al);
        ar = fmaf(hv.x, wr.x, ar); ar = fmaf(hv.y, wr.y, ar);
        ar = fmaf(hv.z, wr.z, ar); ar = fmaf(hv.w, wr.w, ar);
    }
    xl2[(size_t)node * 32 + L] = __float2half_rn(al);
    xr2[(size_t)node * 32 + L] = ar;
}

// ---- gat2 + decoder: h via LDS exchange; Wd1^T swizzled; in-wave MLP ----
__global__ void gat2_dec_kernel(const unsigned* __restrict__ csr,
                                const __half* __restrict__ xl, const float* __restrict__ xr,
                                const float* __restrict__ We, const float* __restrict__ att,
                                const float* __restrict__ bias,
                                const float* __restrict__ Wd1, const float* __restrict__ bd1,
                                const float* __restrict__ Wd2, const float* __restrict__ bd2,
                                float* __restrict__ out) {
    __shared__ __align__(16) float sWd1[1024];  // Wd1^T [L][cc], swizzled
    __shared__ float sWd2[64];
    __shared__ float4 hbuf[8][8];
    for (int i = threadIdx.x; i < 1024; i += blockDim.x) {
        int cc = i >> 5, Lc = i & 31;
        int p = (((cc >> 2) ^ (Lc & 7)) << 2) | (cc & 3);
        sWd1[Lc * 32 + p] = Wd1[i];
    }
    if (threadIdx.x < 64) sWd2[threadIdx.x] = Wd2[threadIdx.x];
    __syncthreads();
    int t = blockIdx.x * blockDim.x + threadIdx.x;
    int node = t >> 5, L = t & 31;
    if (node >= NN) return;                     // grid exact: never taken
    float h[4];
    gat_core4(csr, xl, xr, We, att, bias, node, L, h);
    int nl = threadIdx.x >> 5;
    if (L < 8) hbuf[nl][L] = make_float4(h[0], h[1], h[2], h[3]);
    HBUF_FENCE();
    const float4* hv4 = hbuf[nl];
    const float4* wd4 = (const float4*)(sWd1 + L * 32);
    int swz = L & 7;
    float d1 = bd1[L];
#pragma unroll
    for (int c4 = 0; c4 < 8; c4++) {
        float4 hv = hv4[c4];
        float4 wd = wd4[c4 ^ swz];
        d1 = fmaf(hv.x, wd.x, d1); d1 = fmaf(hv.y, wd.y, d1);
        d1 = fmaf(hv.z, wd.z, d1); d1 = fmaf(hv.w, wd.w, d1);
    }
    float hid = fmaxf(d1, 0.f);
    float o0 = hid * sWd2[L * 2 + 0];
    float o1 = hid * sWd2[L * 2 + 1];
    o0 += __shfl_xor(o0, 1);   o1 += __shfl_xor(o1, 1);
    o0 += __shfl_xor(o0, 2);   o1 += __shfl_xor(o1, 2);
    o0 += __shfl_xor(o0, 4);   o1 += __shfl_xor(o1, 4);
    o0 += __shfl_xor(o0, 8);   o1 += __shfl_xor(o1, 8);
    o0 += __shfl_xor(o0, 16);  o1 += __shfl_xor(o1, 16);
    if (L == 0) {
        out[(size_t)node * 2 + 0] = o0 + bd2[0];
        out[(size_t)node * 2 + 1] = o1 + bd2[1];
    }
}

extern "C" void kernel_launch(void* const* d_in, const int* in_sizes, int n_in,
                              void* d_out, int out_size, void* d_ws, size_t ws_size,
                              hipStream_t stream) {
    const float* x     = (const float*)d_in[0];
    const int*   src   = (const int*)d_in[1];
    const int*   dst   = src + NE;
    const float* eattr = (const float*)d_in[2];
    const float* Wl1 = (const float*)d_in[3],  *bl1 = (const float*)d_in[4];
    const float* Wr1 = (const float*)d_in[5],  *br1 = (const float*)d_in[6];
    const float* We1 = (const float*)d_in[7],  *att1 = (const float*)d_in[8];
    const float* b1  = (const float*)d_in[9];
    const float* Wl2 = (const float*)d_in[10], *bl2 = (const float*)d_in[11];
    const float* Wr2 = (const float*)d_in[12], *br2 = (const float*)d_in[13];
    const float* We2 = (const float*)d_in[14], *att2 = (const float*)d_in[15];
    const float* b2  = (const float*)d_in[16];
    const float* Wd1 = (const float*)d_in[17], *bd1 = (const float*)d_in[18];
    const float* Wd2 = (const float*)d_in[19], *bd2 = (const float*)d_in[20];
    float* out = (float*)d_out;

    // workspace layout (~45 MB)
    char* w = (char*)d_ws;
    unsigned* csr = (unsigned*)w;  w += (size_t)NN * ROWU * 4;   // 25.6 MB
    __half*   xl  = (__half*)w;    w += (size_t)NN * 32 * 2;
    float*    xr  = (float*)w;     w += (size_t)NN * 32 * 4;
    __half*   xl2 = (__half*)w;    w += (size_t)NN * 32 * 2;
    float*    xr2 = (float*)w;     w += (size_t)NN * 32 * 4;

    const int B = 256;
    const int gN32 = (NN * 32) / B;       // 12500
    const int gP   = (NN / 4 * 32) / B;   // 3125 (proj: 4 rows/thread; 512 edges/block)

    // ---- CSR zero (counts live in row word 0) ----
    hipMemsetAsync(csr, 0, (size_t)NN * ROWU * 4, stream);

    // ---- layer 1 projections + CSR scatter (fused, overlapping) ----
    proj_scatter_kernel<128><<<gP, B, 0, stream>>>(x, Wl1, bl1, Wr1, br1, xl, xr,
                                                   src, dst, eattr, csr);

    // ---- layer 1 aggregate + layer 2 projections ----
    gat1_proj2_kernel<<<gN32, B, 0, stream>>>(csr, xl, xr, We1, att1, b1,
                                              Wl2, bl2, Wr2, br2, xl2, xr2);

    // ---- layer 2 aggregate + decoder ----
    gat2_dec_kernel<<<gN32, B, 0, stream>>>(csr, xl2, xr2, We2, att2, b2,
                                            Wd1, bd1, Wd2, bd2, out);
}